// Round 4
// baseline (331.732 us; speedup 1.0000x reference)
//
#include <hip/hip_runtime.h>

#define GDIM 128
#define GMASK 127
#define NCELLS (GDIM * GDIM * GDIM)
#define INV_CELL 120.0f
#define EPS 1e-9f

#define BDIM 16                    // 8^3-cell blocks per axis
#define NBINS (BDIM * BDIM * BDIM) // 4096
#define CAP 400                    // Poisson(296): P(overflow) ~ 3e-6, guarded

// Bin record (32 B, one full sector, interleaved):
//   rec[2s]   = {rx, ry, rz, bitcast(orig_idx)}   (r = pos * INV_CELL)
//   rec[2s+1] = {vx, vy, vz, mass}

// ---------------- single-pass binning scatter ----------------
__global__ __launch_bounds__(256) void scatter_kernel(const float* __restrict__ pos,
                                                      const float* __restrict__ vel,
                                                      const float* __restrict__ mass,
                                                      unsigned int* __restrict__ fill,
                                                      float4* __restrict__ rec,
                                                      int n) {
    int i = blockIdx.x * blockDim.x + threadIdx.x;
    if (i >= n) return;
    float rx = pos[3 * i + 0] * INV_CELL;
    float ry = pos[3 * i + 1] * INV_CELL;
    float rz = pos[3 * i + 2] * INV_CELL;
    int bx = (int)floorf(rx), by = (int)floorf(ry), bz = (int)floorf(rz); // 0..119
    int bin = ((bx >> 3) << 8) | ((by >> 3) << 4) | (bz >> 3);
    unsigned int slot = atomicAdd(&fill[bin], 1u);
    if (slot < CAP) {
        size_t base = ((size_t)bin * CAP + slot) * 2;
        rec[base]     = make_float4(rx, ry, rz, __uint_as_float((unsigned int)i));
        rec[base + 1] = make_float4(vel[3 * i + 0], vel[3 * i + 1], vel[3 * i + 2], mass[i]);
    }
}

// ---------------- P2G: one workgroup per 8^3-cell block, LDS grid ----------------
__global__ __launch_bounds__(256) void p2g_lds_kernel(const float4* __restrict__ rec,
                                                      const unsigned int* __restrict__ fill,
                                                      float4* __restrict__ grid) {
    __shared__ float4 node[512];        // 8x8x8 nodes {mass, mx, my, mz}
    __shared__ unsigned int binb[8];    // bin base slot
    __shared__ unsigned int binc[8];    // bin count (clamped)
    __shared__ unsigned int binoff[9];  // prefix over the 8 scanned bins

    int wg = blockIdx.x;
    int Z = wg & 15, Y = (wg >> 4) & 15, X = wg >> 8;
    int t = threadIdx.x;

    for (int idx = t; idx < 512; idx += 256) node[idx] = make_float4(0.f, 0.f, 0.f, 0.f);
    if (t < 8) {
        int dx = (t >> 2) & 1, dy = (t >> 1) & 1, dz = t & 1;
        int bX = X - dx, bY = Y - dy, bZ = Z - dz;
        unsigned int c = 0, b = 0;
        if (bX >= 0 && bY >= 0 && bZ >= 0) {
            int nb = (bX << 8) | (bY << 4) | bZ;
            c = fill[nb];
            if (c > CAP) c = CAP;
            b = (unsigned int)nb * CAP;
        }
        binb[t] = b;
        binc[t] = c;
    }
    __syncthreads();
    if (t == 0) {
        unsigned int s = 0;
        for (int j = 0; j < 8; ++j) { binoff[j] = s; s += binc[j]; }
        binoff[8] = s;
    }
    __syncthreads();
    unsigned int total = binoff[8];

    // contributing cells: [8X-1, 8X+7] per dim
    int clx = 8 * X - 1, cly = 8 * Y - 1, clz = 8 * Z - 1;

    for (unsigned int q = t; q < total; q += 256) {
        int j = 0;
        while (q >= binoff[j + 1]) ++j;
        unsigned int k = binb[j] + (q - binoff[j]);
        float4 a = rec[(size_t)k * 2];
        int cx = (int)floorf(a.x), cy = (int)floorf(a.y), cz = (int)floorf(a.z);
        if (cx < clx || cx > clx + 8 || cy < cly || cy > cly + 8 || cz < clz || cz > clz + 8)
            continue;
        float4 b = rec[(size_t)k * 2 + 1];
        float fx = a.x - (float)cx, fy = a.y - (float)cy, fz = a.z - (float)cz;
        float m = b.w;
        float wxa[2] = {1.0f - fx, fx};
        float wya[2] = {1.0f - fy, fy};
        float wza[2] = {1.0f - fz, fz};
        int lx0 = cx - 8 * X, ly0 = cy - 8 * Y, lz0 = cz - 8 * Z;  // in [-1,7]
#pragma unroll
        for (int ii = 0; ii < 2; ++ii) {
            int lx = lx0 + ii;
            if ((unsigned)lx >= 8u) continue;
#pragma unroll
            for (int jj = 0; jj < 2; ++jj) {
                int ly = ly0 + jj;
                if ((unsigned)ly >= 8u) continue;
#pragma unroll
                for (int kk = 0; kk < 2; ++kk) {
                    int lz = lz0 + kk;
                    if ((unsigned)lz >= 8u) continue;
                    float w = wxa[ii] * wya[jj] * wza[kk] * m;
                    int nidx = ((lx << 3) | ly) << 3 | lz;
                    atomicAdd(&node[nidx].x, w);
                    atomicAdd(&node[nidx].y, w * b.x);
                    atomicAdd(&node[nidx].z, w * b.y);
                    atomicAdd(&node[nidx].w, w * b.z);
                }
            }
        }
    }
    __syncthreads();

    for (int idx = t; idx < 512; idx += 256) {
        float4 g = node[idx];
        float inv = 1.0f / fmaxf(g.x, EPS);
        int lz = idx & 7, ly = (idx >> 3) & 7, lx = idx >> 6;
        int gx = 8 * X + lx, gy = 8 * Y + ly, gz = 8 * Z + lz;
        grid[(((gx << 7) | gy) << 7) | gz] = make_float4(g.y * inv, g.z * inv, g.w * inv, 0.0f);
    }
}

// ---------------- G2P: one workgroup per bin (contiguous points) ----------------
__global__ __launch_bounds__(256) void g2p_bin_kernel(const float4* __restrict__ rec,
                                                      const unsigned int* __restrict__ fill,
                                                      const float4* __restrict__ grid,
                                                      float* __restrict__ out) {
    int bin = blockIdx.x;
    unsigned int cnt = fill[bin];
    if (cnt > CAP) cnt = CAP;
    unsigned int base = (unsigned int)bin * CAP;
    for (unsigned int k = threadIdx.x; k < cnt; k += 256) {
        float4 a = rec[(size_t)(base + k) * 2];
        int bx = (int)floorf(a.x), by = (int)floorf(a.y), bz = (int)floorf(a.z);
        float fx = a.x - (float)bx, fy = a.y - (float)by, fz = a.z - (float)bz;
        float wx[2] = {1.0f - fx, fx};
        float wy[2] = {1.0f - fy, fy};
        float wz[2] = {1.0f - fz, fz};
        float ox = 0.f, oy = 0.f, oz = 0.f;
#pragma unroll
        for (int i = 0; i < 2; ++i) {
#pragma unroll
            for (int j = 0; j < 2; ++j) {
#pragma unroll
                for (int l = 0; l < 2; ++l) {
                    int node = (((((bx + i) & GMASK) << 7) | ((by + j) & GMASK)) << 7) | ((bz + l) & GMASK);
                    float w = wx[i] * wy[j] * wz[l];
                    float4 g = grid[node];
                    ox += w * g.x;
                    oy += w * g.y;
                    oz += w * g.z;
                }
            }
        }
        unsigned int oi = __float_as_uint(a.w);
        out[3 * (size_t)oi + 0] = ox;
        out[3 * (size_t)oi + 1] = oy;
        out[3 * (size_t)oi + 2] = oz;
    }
}

// ---------------- fallback (atomic path, needs only 32 MiB) ----------------
__global__ __launch_bounds__(256) void p2g_atomic_kernel(const float* __restrict__ pos,
                                                         const float* __restrict__ vel,
                                                         const float* __restrict__ mass,
                                                         float4* __restrict__ grid, int n) {
    int i = blockIdx.x * blockDim.x + threadIdx.x;
    if (i >= n) return;
    float rx = pos[3 * i] * INV_CELL, ry = pos[3 * i + 1] * INV_CELL, rz = pos[3 * i + 2] * INV_CELL;
    int bx = (int)floorf(rx), by = (int)floorf(ry), bz = (int)floorf(rz);
    float wx[2] = {1.0f - (rx - bx), rx - bx}, wy[2] = {1.0f - (ry - by), ry - by}, wz[2] = {1.0f - (rz - bz), rz - bz};
    float m = mass[i], vx = vel[3 * i], vy = vel[3 * i + 1], vz = vel[3 * i + 2];
#pragma unroll
    for (int a = 0; a < 2; ++a)
#pragma unroll
        for (int b = 0; b < 2; ++b)
#pragma unroll
            for (int c = 0; c < 2; ++c) {
                float w = wx[a] * wy[b] * wz[c] * m;
                int idx = (((((bx + a) & GMASK) << 7) | ((by + b) & GMASK)) << 7) | ((bz + c) & GMASK);
                float* cell = (float*)(grid + idx);
                atomicAdd(cell + 0, w);
                atomicAdd(cell + 1, w * vx);
                atomicAdd(cell + 2, w * vy);
                atomicAdd(cell + 3, w * vz);
            }
}

__global__ __launch_bounds__(256) void gridvel_kernel(float4* __restrict__ grid) {
    int i = blockIdx.x * blockDim.x + threadIdx.x;
    if (i >= NCELLS) return;
    float4 g = grid[i];
    float inv = 1.0f / fmaxf(g.x, EPS);
    grid[i] = make_float4(g.y * inv, g.z * inv, g.w * inv, 0.0f);
}

__global__ __launch_bounds__(256) void g2p_plain_kernel(const float* __restrict__ pos,
                                                        const float4* __restrict__ grid,
                                                        float* __restrict__ out, int n) {
    int i = blockIdx.x * blockDim.x + threadIdx.x;
    if (i >= n) return;
    float rx = pos[3 * i] * INV_CELL, ry = pos[3 * i + 1] * INV_CELL, rz = pos[3 * i + 2] * INV_CELL;
    int bx = (int)floorf(rx), by = (int)floorf(ry), bz = (int)floorf(rz);
    float wx[2] = {1.0f - (rx - bx), rx - bx}, wy[2] = {1.0f - (ry - by), ry - by}, wz[2] = {1.0f - (rz - bz), rz - bz};
    float ox = 0, oy = 0, oz = 0;
#pragma unroll
    for (int a = 0; a < 2; ++a)
#pragma unroll
        for (int b = 0; b < 2; ++b)
#pragma unroll
            for (int c = 0; c < 2; ++c) {
                float w = wx[a] * wy[b] * wz[c];
                int idx = (((((bx + a) & GMASK) << 7) | ((by + b) & GMASK)) << 7) | ((bz + c) & GMASK);
                float4 g = grid[idx];
                ox += w * g.x; oy += w * g.y; oz += w * g.z;
            }
    out[3 * i] = ox; out[3 * i + 1] = oy; out[3 * i + 2] = oz;
}

extern "C" void kernel_launch(void* const* d_in, const int* in_sizes, int n_in,
                              void* d_out, int out_size, void* d_ws, size_t ws_size,
                              hipStream_t stream) {
    const float* pos  = (const float*)d_in[0];
    const float* vel  = (const float*)d_in[1];
    const float* mass = (const float*)d_in[2];
    float* out = (float*)d_out;
    int n = in_sizes[2];

    char* ws = (char*)d_ws;
    size_t off = 0;
    unsigned int* fill = (unsigned int*)(ws + off); off += (size_t)NBINS * 4;        // 16 KiB
    float4* grid = (float4*)(ws + off);             off += (size_t)NCELLS * 16;      // 32 MiB
    float4* rec  = (float4*)(ws + off);             off += (size_t)NBINS * CAP * 32; // 50 MiB
    size_t need = off;

    int pblocks = (n + 255) / 256;

    if (ws_size < need) {
        // fallback: atomic scatter path (needs only the 32 MiB grid at ws start)
        float4* g0 = (float4*)d_ws;
        hipMemsetAsync(d_ws, 0, (size_t)NCELLS * 16, stream);
        p2g_atomic_kernel<<<pblocks, 256, 0, stream>>>(pos, vel, mass, g0, n);
        gridvel_kernel<<<NCELLS / 256, 256, 0, stream>>>(g0);
        g2p_plain_kernel<<<pblocks, 256, 0, stream>>>(pos, g0, out, n);
        return;
    }

    hipMemsetAsync(fill, 0, (size_t)NBINS * 4, stream);
    scatter_kernel<<<pblocks, 256, 0, stream>>>(pos, vel, mass, fill, rec, n);
    p2g_lds_kernel<<<NBINS, 256, 0, stream>>>(rec, fill, grid);
    g2p_bin_kernel<<<NBINS, 256, 0, stream>>>(rec, fill, grid, out);
}

// Round 5
// 198.155 us; speedup vs baseline: 1.6741x; 1.6741x over previous
//
#include <hip/hip_runtime.h>

#define GDIM 128
#define GMASK 127
#define NCELLS (GDIM * GDIM * GDIM)
#define INV_CELL 120.0f
#define EPS 1e-9f

#define BDIM 16                    // 8^3-cell blocks per axis
#define NBINS (BDIM * BDIM * BDIM) // 4096
#define CAP 400                    // Poisson(296): P(overflow) ~ 1e-6/bin, guarded
#define SPB 513                    // starts entries per bin (512 cells + end sentinel)

// Bin record (32 B, one sector, interleaved):
//   rec[2s]   = {rx, ry, rz, bitcast(orig_idx)}   (r = pos * INV_CELL)
//   rec[2s+1] = {vx, vy, vz, mass}
// After binsort_kernel, records within a bin are sorted by local cell
// li = (lx<<6)|(ly<<3)|lz and binstarts[bin*SPB + li] gives the global slot
// start of that cell's points (binstarts[bin*SPB+512] = bin end).

// ---------------- single-pass binning scatter ----------------
__global__ __launch_bounds__(256) void scatter_kernel(const float* __restrict__ pos,
                                                      const float* __restrict__ vel,
                                                      const float* __restrict__ mass,
                                                      unsigned int* __restrict__ fill,
                                                      float4* __restrict__ rec,
                                                      int n) {
    int i = blockIdx.x * blockDim.x + threadIdx.x;
    if (i >= n) return;
    float rx = pos[3 * i + 0] * INV_CELL;
    float ry = pos[3 * i + 1] * INV_CELL;
    float rz = pos[3 * i + 2] * INV_CELL;
    int bx = (int)floorf(rx), by = (int)floorf(ry), bz = (int)floorf(rz); // 0..119
    int bin = ((bx >> 3) << 8) | ((by >> 3) << 4) | (bz >> 3);
    unsigned int slot = atomicAdd(&fill[bin], 1u);
    if (slot < CAP) {
        size_t base = ((size_t)bin * CAP + slot) * 2;
        rec[base]     = make_float4(rx, ry, rz, __uint_as_float((unsigned int)i));
        rec[base + 1] = make_float4(vel[3 * i + 0], vel[3 * i + 1], vel[3 * i + 2], mass[i]);
    }
}

// ---------------- per-bin in-LDS counting sort by cell ----------------
__global__ __launch_bounds__(256) void binsort_kernel(const unsigned int* __restrict__ fill,
                                                      float4* __restrict__ rec,
                                                      unsigned int* __restrict__ binstarts) {
    __shared__ float4 stage[CAP * 2];        // 12.8 KB
    __shared__ unsigned int code[CAP];       // (li<<8)|slot
    __shared__ unsigned int ccount[512];
    __shared__ unsigned int cstart[513];
    __shared__ unsigned int sh[256];

    int bin = blockIdx.x;
    int t = threadIdx.x;
    unsigned int cnt = fill[bin];
    if (cnt > CAP) cnt = CAP;
    ccount[t] = 0;
    ccount[t + 256] = 0;
    __syncthreads();

    size_t base2 = (size_t)bin * CAP * 2;
    for (unsigned int k = t; k < cnt; k += 256) {
        float4 a = rec[base2 + 2 * k];
        float4 b = rec[base2 + 2 * k + 1];
        stage[2 * k] = a;
        stage[2 * k + 1] = b;
        int lx = ((int)a.x) & 7;   // a.* >= 0, truncation == floor
        int ly = ((int)a.y) & 7;
        int lz = ((int)a.z) & 7;
        unsigned int li = (unsigned)((lx << 6) | (ly << 3) | lz);
        unsigned int slot = atomicAdd(&ccount[li], 1u);
        code[k] = (li << 8) | slot;   // per-cell count ~Poisson(0.58) << 256
    }
    __syncthreads();

    // exclusive scan of ccount[512] -> cstart (2 elems/thread + Hillis-Steele)
    unsigned int c0 = ccount[2 * t], c1 = ccount[2 * t + 1], s = c0 + c1;
    sh[t] = s;
    __syncthreads();
#pragma unroll
    for (int off = 1; off < 256; off <<= 1) {
        unsigned int add = (t >= off) ? sh[t - off] : 0u;
        __syncthreads();
        sh[t] += add;
        __syncthreads();
    }
    unsigned int pre = sh[t] - s;
    cstart[2 * t] = pre;
    cstart[2 * t + 1] = pre + c0;
    if (t == 255) cstart[512] = cnt;
    __syncthreads();

    // write back sorted (in place: all data is staged in LDS)
    for (unsigned int k = t; k < cnt; k += 256) {
        unsigned int cd = code[k];
        unsigned int dst = cstart[cd >> 8] + (cd & 255u);
        rec[base2 + 2 * dst]     = stage[2 * k];
        rec[base2 + 2 * dst + 1] = stage[2 * k + 1];
    }
    unsigned int bb = (unsigned)bin * CAP;
    for (int i = t; i < SPB; i += 256)
        binstarts[(size_t)bin * SPB + i] = bb + cstart[i];
}

// ---------------- P2G: node-per-thread exact cell spans, no atomics ----------------
__global__ __launch_bounds__(256) void p2g_kernelC(const float4* __restrict__ rec,
                                                   const unsigned int* __restrict__ binstarts,
                                                   float4* __restrict__ grid) {
    int node = blockIdx.x * blockDim.x + threadIdx.x;
    int z = node & GMASK, y = (node >> 7) & GMASK, x = node >> 14;
    float macc = 0.f, mx = 0.f, my = 0.f, mz = 0.f;
#pragma unroll
    for (int dx = 0; dx < 2; ++dx) {
        int cx = x - dx;
        if ((unsigned)cx >= 120u) continue;      // cells span 0..119
        int bX = cx >> 3, lx = cx & 7;
#pragma unroll
        for (int dy = 0; dy < 2; ++dy) {
            int cy = y - dy;
            if ((unsigned)cy >= 120u) continue;
            int bY = cy >> 3, ly = cy & 7;
#pragma unroll
            for (int dz = 0; dz < 2; ++dz) {
                int cz = z - dz;
                if ((unsigned)cz >= 120u) continue;
                int bin = (bX << 8) | (bY << 4) | (cz >> 3);
                int li = (lx << 6) | (ly << 3) | (cz & 7);
                const unsigned int* bs = binstarts + (size_t)bin * SPB + li;
                unsigned int s0 = bs[0], e0 = bs[1];
                for (unsigned int k = s0; k < e0; ++k) {
                    float4 a = rec[2 * (size_t)k];
                    float4 b = rec[2 * (size_t)k + 1];
                    float fx = a.x - (float)cx;   // cell known -> no floor
                    float fy = a.y - (float)cy;
                    float fz = a.z - (float)cz;
                    float wx = dx ? fx : 1.0f - fx;
                    float wy = dy ? fy : 1.0f - fy;
                    float wz = dz ? fz : 1.0f - fz;
                    float w = wx * wy * wz * b.w;
                    macc += w;
                    mx += w * b.x;
                    my += w * b.y;
                    mz += w * b.z;
                }
            }
        }
    }
    float inv = 1.0f / fmaxf(macc, EPS);
    grid[node] = make_float4(mx * inv, my * inv, mz * inv, 0.0f);
}

// ---------------- G2P: one workgroup per bin (contiguous sorted points) ----------------
__global__ __launch_bounds__(256) void g2p_kernelC(const float4* __restrict__ rec,
                                                   const unsigned int* __restrict__ binstarts,
                                                   const float4* __restrict__ grid,
                                                   float* __restrict__ out) {
    int bin = blockIdx.x;
    unsigned int bb = (unsigned)bin * CAP;
    unsigned int cnt = binstarts[(size_t)bin * SPB + 512] - bb;
    for (unsigned int k = threadIdx.x; k < cnt; k += 256) {
        float4 a = rec[(size_t)(bb + k) * 2];
        int bx = (int)floorf(a.x), by = (int)floorf(a.y), bz = (int)floorf(a.z);
        float fx = a.x - (float)bx, fy = a.y - (float)by, fz = a.z - (float)bz;
        float wx[2] = {1.0f - fx, fx};
        float wy[2] = {1.0f - fy, fy};
        float wz[2] = {1.0f - fz, fz};
        float ox = 0.f, oy = 0.f, oz = 0.f;
#pragma unroll
        for (int i = 0; i < 2; ++i) {
#pragma unroll
            for (int j = 0; j < 2; ++j) {
#pragma unroll
                for (int l = 0; l < 2; ++l) {
                    int node = (((((bx + i) & GMASK) << 7) | ((by + j) & GMASK)) << 7) | ((bz + l) & GMASK);
                    float w = wx[i] * wy[j] * wz[l];
                    float4 g = grid[node];
                    ox += w * g.x;
                    oy += w * g.y;
                    oz += w * g.z;
                }
            }
        }
        unsigned int oi = __float_as_uint(a.w);
        out[3 * (size_t)oi + 0] = ox;
        out[3 * (size_t)oi + 1] = oy;
        out[3 * (size_t)oi + 2] = oz;
    }
}

// ---------------- fallback (atomic path, needs only 32 MiB) ----------------
__global__ __launch_bounds__(256) void p2g_atomic_kernel(const float* __restrict__ pos,
                                                         const float* __restrict__ vel,
                                                         const float* __restrict__ mass,
                                                         float4* __restrict__ grid, int n) {
    int i = blockIdx.x * blockDim.x + threadIdx.x;
    if (i >= n) return;
    float rx = pos[3 * i] * INV_CELL, ry = pos[3 * i + 1] * INV_CELL, rz = pos[3 * i + 2] * INV_CELL;
    int bx = (int)floorf(rx), by = (int)floorf(ry), bz = (int)floorf(rz);
    float wx[2] = {1.0f - (rx - bx), rx - bx}, wy[2] = {1.0f - (ry - by), ry - by}, wz[2] = {1.0f - (rz - bz), rz - bz};
    float m = mass[i], vx = vel[3 * i], vy = vel[3 * i + 1], vz = vel[3 * i + 2];
#pragma unroll
    for (int a = 0; a < 2; ++a)
#pragma unroll
        for (int b = 0; b < 2; ++b)
#pragma unroll
            for (int c = 0; c < 2; ++c) {
                float w = wx[a] * wy[b] * wz[c] * m;
                int idx = (((((bx + a) & GMASK) << 7) | ((by + b) & GMASK)) << 7) | ((bz + c) & GMASK);
                float* cell = (float*)(grid + idx);
                atomicAdd(cell + 0, w);
                atomicAdd(cell + 1, w * vx);
                atomicAdd(cell + 2, w * vy);
                atomicAdd(cell + 3, w * vz);
            }
}

__global__ __launch_bounds__(256) void gridvel_kernel(float4* __restrict__ grid) {
    int i = blockIdx.x * blockDim.x + threadIdx.x;
    if (i >= NCELLS) return;
    float4 g = grid[i];
    float inv = 1.0f / fmaxf(g.x, EPS);
    grid[i] = make_float4(g.y * inv, g.z * inv, g.w * inv, 0.0f);
}

__global__ __launch_bounds__(256) void g2p_plain_kernel(const float* __restrict__ pos,
                                                        const float4* __restrict__ grid,
                                                        float* __restrict__ out, int n) {
    int i = blockIdx.x * blockDim.x + threadIdx.x;
    if (i >= n) return;
    float rx = pos[3 * i] * INV_CELL, ry = pos[3 * i + 1] * INV_CELL, rz = pos[3 * i + 2] * INV_CELL;
    int bx = (int)floorf(rx), by = (int)floorf(ry), bz = (int)floorf(rz);
    float wx[2] = {1.0f - (rx - bx), rx - bx}, wy[2] = {1.0f - (ry - by), ry - by}, wz[2] = {1.0f - (rz - bz), rz - bz};
    float ox = 0, oy = 0, oz = 0;
#pragma unroll
    for (int a = 0; a < 2; ++a)
#pragma unroll
        for (int b = 0; b < 2; ++b)
#pragma unroll
            for (int c = 0; c < 2; ++c) {
                float w = wx[a] * wy[b] * wz[c];
                int idx = (((((bx + a) & GMASK) << 7) | ((by + b) & GMASK)) << 7) | ((bz + c) & GMASK);
                float4 g = grid[idx];
                ox += w * g.x; oy += w * g.y; oz += w * g.z;
            }
    out[3 * i] = ox; out[3 * i + 1] = oy; out[3 * i + 2] = oz;
}

extern "C" void kernel_launch(void* const* d_in, const int* in_sizes, int n_in,
                              void* d_out, int out_size, void* d_ws, size_t ws_size,
                              hipStream_t stream) {
    const float* pos  = (const float*)d_in[0];
    const float* vel  = (const float*)d_in[1];
    const float* mass = (const float*)d_in[2];
    float* out = (float*)d_out;
    int n = in_sizes[2];

    char* ws = (char*)d_ws;
    size_t off = 0;
    unsigned int* fill = (unsigned int*)(ws + off);      off += (size_t)NBINS * 4;        // 16 KiB
    float4* grid = (float4*)(ws + off);                  off += (size_t)NCELLS * 16;      // 32 MiB
    float4* rec  = (float4*)(ws + off);                  off += (size_t)NBINS * CAP * 32; // 50 MiB
    unsigned int* binstarts = (unsigned int*)(ws + off); off += (size_t)NBINS * SPB * 4;  // 8.4 MiB
    size_t need = off;

    int pblocks = (n + 255) / 256;

    if (ws_size < need) {
        float4* g0 = (float4*)d_ws;
        hipMemsetAsync(d_ws, 0, (size_t)NCELLS * 16, stream);
        p2g_atomic_kernel<<<pblocks, 256, 0, stream>>>(pos, vel, mass, g0, n);
        gridvel_kernel<<<NCELLS / 256, 256, 0, stream>>>(g0);
        g2p_plain_kernel<<<pblocks, 256, 0, stream>>>(pos, g0, out, n);
        return;
    }

    hipMemsetAsync(fill, 0, (size_t)NBINS * 4, stream);
    scatter_kernel<<<pblocks, 256, 0, stream>>>(pos, vel, mass, fill, rec, n);
    binsort_kernel<<<NBINS, 256, 0, stream>>>(fill, rec, binstarts);
    p2g_kernelC<<<NCELLS / 256, 256, 0, stream>>>(rec, binstarts, grid);
    g2p_kernelC<<<NBINS, 256, 0, stream>>>(rec, binstarts, grid, out);
}

// Round 7
// 183.414 us; speedup vs baseline: 1.8087x; 1.0804x over previous
//
#include <hip/hip_runtime.h>

#define GDIM 128
#define GMASK 127
#define NCELLS (GDIM * GDIM * GDIM)
#define INV_CELL 120.0f
#define EPS 1e-9f

#define BDIM 16                    // 8^3-cell blocks per axis
#define NBINS (BDIM * BDIM * BDIM) // 4096
#define SPB 513                    // starts entries per bin (512 cells + end)
#define STCAP 448                  // binsort LDS stage capacity (bin ~Binom mean 296, sd 17)
#define NCHUNK 512                 // point chunks (one block each in hist/scatter)

// Dense record (32 B, interleaved):
//   rec[2s]   = {rx, ry, rz, bitcast(orig_idx)}   (r = pos * INV_CELL)
//   rec[2s+1] = {vx, vy, vz, mass}
// Bin b owns slots [binPrefix[b], binPrefix[b+1]); after binsort, records in a
// bin are sorted by (local cell, orig_idx) — a CANONICAL order, so the whole
// pipeline is bitwise deterministic regardless of atomic arrival order.

// ---------------- pass 1: per-chunk LDS histogram (no global atomics) ----------------
__global__ __launch_bounds__(256) void hist_kernel(const float* __restrict__ pos,
                                                   unsigned int* __restrict__ cnt,
                                                   int n, int chunk) {
    __shared__ unsigned int lh[NBINS];   // 16 KB
    int c = blockIdx.x, t = threadIdx.x;
    for (int j = t; j < NBINS; j += 256) lh[j] = 0;
    __syncthreads();
    int s = c * chunk, e = min(n, s + chunk);
    for (int i = s + t; i < e; i += 256) {
        int bx = (int)(pos[3 * i + 0] * INV_CELL);   // pos >= 0: trunc == floor
        int by = (int)(pos[3 * i + 1] * INV_CELL);
        int bz = (int)(pos[3 * i + 2] * INV_CELL);
        int bin = ((bx >> 3) << 8) | ((by >> 3) << 4) | (bz >> 3);
        atomicAdd(&lh[bin], 1u);
    }
    __syncthreads();
    unsigned int* row = cnt + (size_t)c * NBINS;
    for (int j = t; j < NBINS; j += 256) row[j] = lh[j];
}

// ---------------- pass 2a: column scan over [NCHUNK][NBINS] ----------------
__global__ __launch_bounds__(256) void scan_cols_kernel(const unsigned int* __restrict__ cnt,
                                                        unsigned int* __restrict__ offs,
                                                        unsigned int* __restrict__ binTotal) {
    int col = blockIdx.x * 256 + threadIdx.x;   // 4096 threads, one column each
    unsigned int acc = 0;
#pragma unroll 8
    for (int r = 0; r < NCHUNK; ++r) {
        unsigned int v = cnt[(size_t)r * NBINS + col];
        offs[(size_t)r * NBINS + col] = acc;
        acc += v;
    }
    binTotal[col] = acc;
}

// ---------------- pass 2b: exclusive scan over 4096 bin totals ----------------
__global__ __launch_bounds__(256) void scan_bins_kernel(const unsigned int* __restrict__ binTotal,
                                                        unsigned int* __restrict__ binPrefix,
                                                        int n) {
    __shared__ unsigned int sh[256];
    int t = threadIdx.x;
    unsigned int e[16], s = 0;
#pragma unroll
    for (int j = 0; j < 16; ++j) { e[j] = binTotal[t * 16 + j]; s += e[j]; }
    sh[t] = s;
    __syncthreads();
#pragma unroll
    for (int off = 1; off < 256; off <<= 1) {
        unsigned int add = (t >= off) ? sh[t - off] : 0u;
        __syncthreads();
        sh[t] += add;
        __syncthreads();
    }
    unsigned int run = sh[t] - s;
#pragma unroll
    for (int j = 0; j < 16; ++j) { binPrefix[t * 16 + j] = run; run += e[j]; }
    if (t == 255) binPrefix[NBINS] = (unsigned int)n;
}

// ---------------- pass 3: dense scatter (LDS offsets; slot order canonicalized later) ----------------
__global__ __launch_bounds__(256) void scatter_dense_kernel(const float* __restrict__ pos,
                                                            const float* __restrict__ vel,
                                                            const float* __restrict__ mass,
                                                            const unsigned int* __restrict__ offs,
                                                            const unsigned int* __restrict__ binPrefix,
                                                            float4* __restrict__ rec,
                                                            int n, int chunk) {
    __shared__ unsigned int lof[NBINS];   // 16 KB
    int c = blockIdx.x, t = threadIdx.x;
    const unsigned int* row = offs + (size_t)c * NBINS;
    for (int j = t; j < NBINS; j += 256) lof[j] = row[j] + binPrefix[j];
    __syncthreads();
    int s = c * chunk, e = min(n, s + chunk);
    for (int i = s + t; i < e; i += 256) {
        float rx = pos[3 * i + 0] * INV_CELL;
        float ry = pos[3 * i + 1] * INV_CELL;
        float rz = pos[3 * i + 2] * INV_CELL;
        int bin = ((((int)rx) >> 3) << 8) | ((((int)ry) >> 3) << 4) | (((int)rz) >> 3);
        unsigned int slot = atomicAdd(&lof[bin], 1u);
        size_t b2 = (size_t)slot * 2;
        rec[b2]     = make_float4(rx, ry, rz, __uint_as_float((unsigned int)i));
        rec[b2 + 1] = make_float4(vel[3 * i + 0], vel[3 * i + 1], vel[3 * i + 2], mass[i]);
    }
}

// ---------------- per-bin in-LDS counting sort by (cell, orig_idx) — DETERMINISTIC ----------------
__global__ __launch_bounds__(256) void binsort_kernel(const unsigned int* __restrict__ binPrefix,
                                                      float4* __restrict__ rec,
                                                      unsigned int* __restrict__ binstarts) {
    __shared__ float4 stage[STCAP * 2];      // 14.3 KB
    __shared__ unsigned int codeLi[STCAP];   // cell of staged point k
    __shared__ unsigned int dstA[STCAP];     // provisional slot, then final dst
    __shared__ unsigned int perm[STCAP];     // provisional dst -> k
    __shared__ unsigned int ccount[512];
    __shared__ unsigned int cstart[513];
    __shared__ unsigned int sh[256];

    int bin = blockIdx.x;
    int t = threadIdx.x;
    unsigned int base = binPrefix[bin];
    unsigned int cnt = binPrefix[bin + 1] - base;
    if (cnt > STCAP) cnt = STCAP;            // statistically never (8.8 sigma)
    ccount[t] = 0;
    ccount[t + 256] = 0;
    __syncthreads();

    size_t b2 = (size_t)base * 2;
    // A: stage + provisional per-cell slot (arrival order — canonicalized below)
    for (unsigned int k = t; k < cnt; k += 256) {
        float4 a = rec[b2 + 2 * k];
        float4 b = rec[b2 + 2 * k + 1];
        stage[2 * k] = a;
        stage[2 * k + 1] = b;
        int li = ((((int)a.x) & 7) << 6) | ((((int)a.y) & 7) << 3) | (((int)a.z) & 7);
        codeLi[k] = (unsigned)li;
        dstA[k] = atomicAdd(&ccount[li], 1u);   // provisional slot within cell
    }
    __syncthreads();

    // exclusive scan of ccount[512] -> cstart (deterministic: counts only)
    unsigned int c0 = ccount[2 * t], c1 = ccount[2 * t + 1], s = c0 + c1;
    sh[t] = s;
    __syncthreads();
#pragma unroll
    for (int off = 1; off < 256; off <<= 1) {
        unsigned int add = (t >= off) ? sh[t - off] : 0u;
        __syncthreads();
        sh[t] += add;
        __syncthreads();
    }
    unsigned int pre = sh[t] - s;
    cstart[2 * t] = pre;
    cstart[2 * t + 1] = pre + c0;
    if (t == 255) cstart[512] = cnt;
    __syncthreads();

    // build provisional inverse map perm[cstart[li] + slot] = k
    for (unsigned int k = t; k < cnt; k += 256)
        perm[cstart[codeLi[k]] + dstA[k]] = k;
    __syncthreads();

    // B: canonical rank within each cell by orig_idx (O(c^2), c ~ Poisson(0.58))
    for (int cell = t; cell < 512; cell += 256) {
        unsigned int c = ccount[cell];
        if (c == 0) continue;
        unsigned int s0 = cstart[cell];
        for (unsigned int a = 0; a < c; ++a) {
            unsigned int ka = perm[s0 + a];
            unsigned int oia = __float_as_uint(stage[2 * ka].w);
            unsigned int r = 0;
            for (unsigned int b = 0; b < c; ++b) {
                unsigned int kb = perm[s0 + b];
                unsigned int oib = __float_as_uint(stage[2 * kb].w);
                r += (oib < oia) ? 1u : 0u;
            }
            dstA[ka] = s0 + r;   // final dst: unique (oi distinct)
        }
    }
    __syncthreads();

    // C: write back in canonical order + binstarts
    for (unsigned int k = t; k < cnt; k += 256) {
        unsigned int dst = dstA[k];
        rec[b2 + 2 * dst]     = stage[2 * k];
        rec[b2 + 2 * dst + 1] = stage[2 * k + 1];
    }
    for (int i = t; i < SPB; i += 256)
        binstarts[(size_t)bin * SPB + i] = base + cstart[i];
}

// ---------------- P2G: node-per-thread exact cell spans, no atomics ----------------
__global__ __launch_bounds__(256) void p2g_kernelC(const float4* __restrict__ rec,
                                                   const unsigned int* __restrict__ binstarts,
                                                   float4* __restrict__ grid) {
    int node = blockIdx.x * blockDim.x + threadIdx.x;
    int z = node & GMASK, y = (node >> 7) & GMASK, x = node >> 14;
    float macc = 0.f, mx = 0.f, my = 0.f, mz = 0.f;
#pragma unroll
    for (int dx = 0; dx < 2; ++dx) {
        int cx = x - dx;
        if ((unsigned)cx >= 120u) continue;      // cells span 0..119
        int bX = cx >> 3, lx = cx & 7;
#pragma unroll
        for (int dy = 0; dy < 2; ++dy) {
            int cy = y - dy;
            if ((unsigned)cy >= 120u) continue;
            int bY = cy >> 3, ly = cy & 7;
#pragma unroll
            for (int dz = 0; dz < 2; ++dz) {
                int cz = z - dz;
                if ((unsigned)cz >= 120u) continue;
                int bin = (bX << 8) | (bY << 4) | (cz >> 3);
                int li = (lx << 6) | (ly << 3) | (cz & 7);
                const unsigned int* bs = binstarts + (size_t)bin * SPB + li;
                unsigned int s0 = bs[0], e0 = bs[1];
                for (unsigned int k = s0; k < e0; ++k) {
                    float4 a = rec[2 * (size_t)k];
                    float4 b = rec[2 * (size_t)k + 1];
                    float fx = a.x - (float)cx;
                    float fy = a.y - (float)cy;
                    float fz = a.z - (float)cz;
                    float wx = dx ? fx : 1.0f - fx;
                    float wy = dy ? fy : 1.0f - fy;
                    float wz = dz ? fz : 1.0f - fz;
                    float w = wx * wy * wz * b.w;
                    macc += w;
                    mx += w * b.x;
                    my += w * b.y;
                    mz += w * b.z;
                }
            }
        }
    }
    float inv = 1.0f / fmaxf(macc, EPS);
    grid[node] = make_float4(mx * inv, my * inv, mz * inv, 0.0f);
}

// ---------------- G2P: one workgroup per bin (contiguous sorted points) ----------------
__global__ __launch_bounds__(256) void g2p_kernelC(const float4* __restrict__ rec,
                                                   const unsigned int* __restrict__ binstarts,
                                                   const float4* __restrict__ grid,
                                                   float* __restrict__ out) {
    int bin = blockIdx.x;
    unsigned int bb = binstarts[(size_t)bin * SPB];
    unsigned int cnt = binstarts[(size_t)bin * SPB + 512] - bb;
    for (unsigned int k = threadIdx.x; k < cnt; k += 256) {
        float4 a = rec[(size_t)(bb + k) * 2];
        int bx = (int)a.x, by = (int)a.y, bz = (int)a.z;
        float fx = a.x - (float)bx, fy = a.y - (float)by, fz = a.z - (float)bz;
        float wx[2] = {1.0f - fx, fx};
        float wy[2] = {1.0f - fy, fy};
        float wz[2] = {1.0f - fz, fz};
        float ox = 0.f, oy = 0.f, oz = 0.f;
#pragma unroll
        for (int i = 0; i < 2; ++i) {
#pragma unroll
            for (int j = 0; j < 2; ++j) {
#pragma unroll
                for (int l = 0; l < 2; ++l) {
                    int node = (((((bx + i) & GMASK) << 7) | ((by + j) & GMASK)) << 7) | ((bz + l) & GMASK);
                    float w = wx[i] * wy[j] * wz[l];
                    float4 g = grid[node];
                    ox += w * g.x;
                    oy += w * g.y;
                    oz += w * g.z;
                }
            }
        }
        unsigned int oi = __float_as_uint(a.w);
        out[3 * (size_t)oi + 0] = ox;
        out[3 * (size_t)oi + 1] = oy;
        out[3 * (size_t)oi + 2] = oz;
    }
}

// ---------------- fallback (atomic path, needs only 32 MiB) ----------------
__global__ __launch_bounds__(256) void p2g_atomic_kernel(const float* __restrict__ pos,
                                                         const float* __restrict__ vel,
                                                         const float* __restrict__ mass,
                                                         float4* __restrict__ grid, int n) {
    int i = blockIdx.x * blockDim.x + threadIdx.x;
    if (i >= n) return;
    float rx = pos[3 * i] * INV_CELL, ry = pos[3 * i + 1] * INV_CELL, rz = pos[3 * i + 2] * INV_CELL;
    int bx = (int)floorf(rx), by = (int)floorf(ry), bz = (int)floorf(rz);
    float wx[2] = {1.0f - (rx - bx), rx - bx}, wy[2] = {1.0f - (ry - by), ry - by}, wz[2] = {1.0f - (rz - bz), rz - bz};
    float m = mass[i], vx = vel[3 * i], vy = vel[3 * i + 1], vz = vel[3 * i + 2];
#pragma unroll
    for (int a = 0; a < 2; ++a)
#pragma unroll
        for (int b = 0; b < 2; ++b)
#pragma unroll
            for (int c = 0; c < 2; ++c) {
                float w = wx[a] * wy[b] * wz[c] * m;
                int idx = (((((bx + a) & GMASK) << 7) | ((by + b) & GMASK)) << 7) | ((bz + c) & GMASK);
                float* cell = (float*)(grid + idx);
                atomicAdd(cell + 0, w);
                atomicAdd(cell + 1, w * vx);
                atomicAdd(cell + 2, w * vy);
                atomicAdd(cell + 3, w * vz);
            }
}

__global__ __launch_bounds__(256) void gridvel_kernel(float4* __restrict__ grid) {
    int i = blockIdx.x * blockDim.x + threadIdx.x;
    if (i >= NCELLS) return;
    float4 g = grid[i];
    float inv = 1.0f / fmaxf(g.x, EPS);
    grid[i] = make_float4(g.y * inv, g.z * inv, g.w * inv, 0.0f);
}

__global__ __launch_bounds__(256) void g2p_plain_kernel(const float* __restrict__ pos,
                                                        const float4* __restrict__ grid,
                                                        float* __restrict__ out, int n) {
    int i = blockIdx.x * blockDim.x + threadIdx.x;
    if (i >= n) return;
    float rx = pos[3 * i] * INV_CELL, ry = pos[3 * i + 1] * INV_CELL, rz = pos[3 * i + 2] * INV_CELL;
    int bx = (int)floorf(rx), by = (int)floorf(ry), bz = (int)floorf(rz);
    float wx[2] = {1.0f - (rx - bx), rx - bx}, wy[2] = {1.0f - (ry - by), ry - by}, wz[2] = {1.0f - (rz - bz), rz - bz};
    float ox = 0, oy = 0, oz = 0;
#pragma unroll
    for (int a = 0; a < 2; ++a)
#pragma unroll
        for (int b = 0; b < 2; ++b)
#pragma unroll
            for (int c = 0; c < 2; ++c) {
                float w = wx[a] * wy[b] * wz[c];
                int idx = (((((bx + a) & GMASK) << 7) | ((by + b) & GMASK)) << 7) | ((bz + c) & GMASK);
                float4 g = grid[idx];
                ox += w * g.x; oy += w * g.y; oz += w * g.z;
            }
    out[3 * i] = ox; out[3 * i + 1] = oy; out[3 * i + 2] = oz;
}

extern "C" void kernel_launch(void* const* d_in, const int* in_sizes, int n_in,
                              void* d_out, int out_size, void* d_ws, size_t ws_size,
                              hipStream_t stream) {
    const float* pos  = (const float*)d_in[0];
    const float* vel  = (const float*)d_in[1];
    const float* mass = (const float*)d_in[2];
    float* out = (float*)d_out;
    int n = in_sizes[2];

    char* ws = (char*)d_ws;
    size_t off = 0;
    float4* grid = (float4*)(ws + off);                  off += (size_t)NCELLS * 16;          // 32 MiB
    float4* rec  = (float4*)(ws + off);                  off += (size_t)n * 32;               // 30.5 MiB
    unsigned int* binstarts = (unsigned int*)(ws + off); off += (size_t)NBINS * SPB * 4;      // 8.4 MiB
    unsigned int* cnt       = (unsigned int*)(ws + off); off += (size_t)NCHUNK * NBINS * 4;   // 8 MiB
    unsigned int* offs      = (unsigned int*)(ws + off); off += (size_t)NCHUNK * NBINS * 4;   // 8 MiB
    unsigned int* binTotal  = (unsigned int*)(ws + off); off += (size_t)NBINS * 4;
    unsigned int* binPrefix = (unsigned int*)(ws + off); off += (size_t)(NBINS + 8) * 4;
    size_t need = off;

    int pblocks = (n + 255) / 256;
    int chunk = (n + NCHUNK - 1) / NCHUNK;

    if (ws_size < need) {
        float4* g0 = (float4*)d_ws;
        hipMemsetAsync(d_ws, 0, (size_t)NCELLS * 16, stream);
        p2g_atomic_kernel<<<pblocks, 256, 0, stream>>>(pos, vel, mass, g0, n);
        gridvel_kernel<<<NCELLS / 256, 256, 0, stream>>>(g0);
        g2p_plain_kernel<<<pblocks, 256, 0, stream>>>(pos, g0, out, n);
        return;
    }

    hist_kernel<<<NCHUNK, 256, 0, stream>>>(pos, cnt, n, chunk);
    scan_cols_kernel<<<NBINS / 256, 256, 0, stream>>>(cnt, offs, binTotal);
    scan_bins_kernel<<<1, 256, 0, stream>>>(binTotal, binPrefix, n);
    scatter_dense_kernel<<<NCHUNK, 256, 0, stream>>>(pos, vel, mass, offs, binPrefix, rec, n, chunk);
    binsort_kernel<<<NBINS, 256, 0, stream>>>(binPrefix, rec, binstarts);
    p2g_kernelC<<<NCELLS / 256, 256, 0, stream>>>(rec, binstarts, grid);
    g2p_kernelC<<<NBINS, 256, 0, stream>>>(rec, binstarts, grid, out);
}

// Round 8
// 169.932 us; speedup vs baseline: 1.9521x; 1.0793x over previous
//
#include <hip/hip_runtime.h>

#define GDIM 128
#define GMASK 127
#define NCELLS (GDIM * GDIM * GDIM)
#define INV_CELL 120.0f
#define EPS 1e-9f

#define BDIM 16                    // 8^3-cell blocks per axis
#define NBINS (BDIM * BDIM * BDIM) // 4096
#define SPB 513                    // starts entries per bin (512 cells + end)
#define STCAP 448                  // binsort LDS stage capacity (bin ~Binom mean 296, sd 17)
#define NCHUNK 512                 // point chunks (one block each in hist/scatter)

// Dense record (32 B, interleaved):
//   rec[2s]   = {rx, ry, rz, bitcast(orig_idx)}   (r = pos * INV_CELL)
//   rec[2s+1] = {vx, vy, vz, mass}
// Bin b owns slots [binPrefix[b], binPrefix[b+1]); after binsort, records in a
// bin are sorted by (local cell, orig_idx) — a CANONICAL order, so the whole
// pipeline is bitwise deterministic regardless of atomic arrival order.

// ---------------- pass 1: per-chunk LDS histogram (no global atomics) ----------------
__global__ __launch_bounds__(256) void hist_kernel(const float* __restrict__ pos,
                                                   unsigned int* __restrict__ cnt,
                                                   int n, int chunk) {
    __shared__ unsigned int lh[NBINS];   // 16 KB
    int c = blockIdx.x, t = threadIdx.x;
    for (int j = t; j < NBINS; j += 256) lh[j] = 0;
    __syncthreads();
    int s = c * chunk, e = min(n, s + chunk);
    for (int i = s + t; i < e; i += 256) {
        int bx = (int)(pos[3 * i + 0] * INV_CELL);   // pos >= 0: trunc == floor
        int by = (int)(pos[3 * i + 1] * INV_CELL);
        int bz = (int)(pos[3 * i + 2] * INV_CELL);
        int bin = ((bx >> 3) << 8) | ((by >> 3) << 4) | (bz >> 3);
        atomicAdd(&lh[bin], 1u);
    }
    __syncthreads();
    unsigned int* row = cnt + (size_t)c * NBINS;
    for (int j = t; j < NBINS; j += 256) row[j] = lh[j];
}

// ---------------- pass 2a: column scan over [NCHUNK][NBINS] ----------------
__global__ __launch_bounds__(256) void scan_cols_kernel(const unsigned int* __restrict__ cnt,
                                                        unsigned int* __restrict__ offs,
                                                        unsigned int* __restrict__ binTotal) {
    int col = blockIdx.x * 256 + threadIdx.x;   // 4096 threads, one column each
    unsigned int acc = 0;
#pragma unroll 8
    for (int r = 0; r < NCHUNK; ++r) {
        unsigned int v = cnt[(size_t)r * NBINS + col];
        offs[(size_t)r * NBINS + col] = acc;
        acc += v;
    }
    binTotal[col] = acc;
}

// ---------------- pass 2b: exclusive scan over 4096 bin totals ----------------
__global__ __launch_bounds__(256) void scan_bins_kernel(const unsigned int* __restrict__ binTotal,
                                                        unsigned int* __restrict__ binPrefix,
                                                        int n) {
    __shared__ unsigned int sh[256];
    int t = threadIdx.x;
    unsigned int e[16], s = 0;
#pragma unroll
    for (int j = 0; j < 16; ++j) { e[j] = binTotal[t * 16 + j]; s += e[j]; }
    sh[t] = s;
    __syncthreads();
#pragma unroll
    for (int off = 1; off < 256; off <<= 1) {
        unsigned int add = (t >= off) ? sh[t - off] : 0u;
        __syncthreads();
        sh[t] += add;
        __syncthreads();
    }
    unsigned int run = sh[t] - s;
#pragma unroll
    for (int j = 0; j < 16; ++j) { binPrefix[t * 16 + j] = run; run += e[j]; }
    if (t == 255) binPrefix[NBINS] = (unsigned int)n;
}

// ---------------- pass 3: dense scatter (LDS offsets; slot order canonicalized later) ----------------
__global__ __launch_bounds__(256) void scatter_dense_kernel(const float* __restrict__ pos,
                                                            const float* __restrict__ vel,
                                                            const float* __restrict__ mass,
                                                            const unsigned int* __restrict__ offs,
                                                            const unsigned int* __restrict__ binPrefix,
                                                            float4* __restrict__ rec,
                                                            int n, int chunk) {
    __shared__ unsigned int lof[NBINS];   // 16 KB
    int c = blockIdx.x, t = threadIdx.x;
    const unsigned int* row = offs + (size_t)c * NBINS;
    for (int j = t; j < NBINS; j += 256) lof[j] = row[j] + binPrefix[j];
    __syncthreads();
    int s = c * chunk, e = min(n, s + chunk);
    for (int i = s + t; i < e; i += 256) {
        float rx = pos[3 * i + 0] * INV_CELL;
        float ry = pos[3 * i + 1] * INV_CELL;
        float rz = pos[3 * i + 2] * INV_CELL;
        int bin = ((((int)rx) >> 3) << 8) | ((((int)ry) >> 3) << 4) | (((int)rz) >> 3);
        unsigned int slot = atomicAdd(&lof[bin], 1u);
        size_t b2 = (size_t)slot * 2;
        rec[b2]     = make_float4(rx, ry, rz, __uint_as_float((unsigned int)i));
        rec[b2 + 1] = make_float4(vel[3 * i + 0], vel[3 * i + 1], vel[3 * i + 2], mass[i]);
    }
}

// ---------------- per-bin in-LDS counting sort by (cell, orig_idx) — DETERMINISTIC ----------------
__global__ __launch_bounds__(256) void binsort_kernel(const unsigned int* __restrict__ binPrefix,
                                                      float4* __restrict__ rec,
                                                      unsigned int* __restrict__ binstarts) {
    __shared__ float4 stage[STCAP * 2];      // 14.3 KB
    __shared__ unsigned int codeLi[STCAP];   // cell of staged point k
    __shared__ unsigned int dstA[STCAP];     // provisional slot, then final dst
    __shared__ unsigned int perm[STCAP];     // provisional dst -> k
    __shared__ unsigned int ccount[512];
    __shared__ unsigned int cstart[513];
    __shared__ unsigned int sh[256];

    int bin = blockIdx.x;
    int t = threadIdx.x;
    unsigned int base = binPrefix[bin];
    unsigned int cnt = binPrefix[bin + 1] - base;
    if (cnt > STCAP) cnt = STCAP;            // statistically never (8.8 sigma)
    ccount[t] = 0;
    ccount[t + 256] = 0;
    __syncthreads();

    size_t b2 = (size_t)base * 2;
    // A: stage + provisional per-cell slot (arrival order — canonicalized below)
    for (unsigned int k = t; k < cnt; k += 256) {
        float4 a = rec[b2 + 2 * k];
        float4 b = rec[b2 + 2 * k + 1];
        stage[2 * k] = a;
        stage[2 * k + 1] = b;
        int li = ((((int)a.x) & 7) << 6) | ((((int)a.y) & 7) << 3) | (((int)a.z) & 7);
        codeLi[k] = (unsigned)li;
        dstA[k] = atomicAdd(&ccount[li], 1u);   // provisional slot within cell
    }
    __syncthreads();

    // exclusive scan of ccount[512] -> cstart (deterministic: counts only)
    unsigned int c0 = ccount[2 * t], c1 = ccount[2 * t + 1], s = c0 + c1;
    sh[t] = s;
    __syncthreads();
#pragma unroll
    for (int off = 1; off < 256; off <<= 1) {
        unsigned int add = (t >= off) ? sh[t - off] : 0u;
        __syncthreads();
        sh[t] += add;
        __syncthreads();
    }
    unsigned int pre = sh[t] - s;
    cstart[2 * t] = pre;
    cstart[2 * t + 1] = pre + c0;
    if (t == 255) cstart[512] = cnt;
    __syncthreads();

    // build provisional inverse map perm[cstart[li] + slot] = k
    for (unsigned int k = t; k < cnt; k += 256)
        perm[cstart[codeLi[k]] + dstA[k]] = k;
    __syncthreads();

    // B: canonical rank within each cell by orig_idx (O(c^2), c ~ Poisson(0.58))
    for (int cell = t; cell < 512; cell += 256) {
        unsigned int c = ccount[cell];
        if (c == 0) continue;
        unsigned int s0 = cstart[cell];
        for (unsigned int a = 0; a < c; ++a) {
            unsigned int ka = perm[s0 + a];
            unsigned int oia = __float_as_uint(stage[2 * ka].w);
            unsigned int r = 0;
            for (unsigned int b = 0; b < c; ++b) {
                unsigned int kb = perm[s0 + b];
                unsigned int oib = __float_as_uint(stage[2 * kb].w);
                r += (oib < oia) ? 1u : 0u;
            }
            dstA[ka] = s0 + r;   // final dst: unique (oi distinct)
        }
    }
    __syncthreads();

    // C: write back in canonical order + binstarts
    for (unsigned int k = t; k < cnt; k += 256) {
        unsigned int dst = dstA[k];
        rec[b2 + 2 * dst]     = stage[2 * k];
        rec[b2 + 2 * dst + 1] = stage[2 * k + 1];
    }
    for (int i = t; i < SPB; i += 256)
        binstarts[(size_t)bin * SPB + i] = base + cstart[i];
}

// ---------------- P2G: 1x2x2 node block per thread, exact cell spans, no atomics ----------------
// Thread owns nodes (x, ny..ny+1, nz..nz+1). Contributing cells: 2x3x3 = 18,
// ~10.4 record loads per 4 nodes (vs 18.6 node-per-thread) and z-spans of 3
// cells merge into 1-2 contiguous record ranges (cell-sorted order).
__global__ __launch_bounds__(256) void p2g_block_kernel(const float4* __restrict__ rec,
                                                        const unsigned int* __restrict__ binstarts,
                                                        float4* __restrict__ grid) {
    int g = blockIdx.x * 256 + threadIdx.x;   // 128 * 64 * 64 = 512K threads
    int Zb = g & 63, Yb = (g >> 6) & 63, x = g >> 12;
    int ny = 2 * Yb, nz = 2 * Zb;

    float4 acc[2][2];                         // [v][w] = {mass, mx, my, mz}
    acc[0][0] = make_float4(0.f, 0.f, 0.f, 0.f);
    acc[0][1] = make_float4(0.f, 0.f, 0.f, 0.f);
    acc[1][0] = make_float4(0.f, 0.f, 0.f, 0.f);
    acc[1][1] = make_float4(0.f, 0.f, 0.f, 0.f);

    int cz_lo = nz - 1; if (cz_lo < 0) cz_lo = 0;
    int cz_hi = nz + 1;                       // <= 127; cells >= 120 are empty
    int bZ0 = cz_lo >> 3, bZ1 = cz_hi >> 3;

#pragma unroll
    for (int dcx = -1; dcx <= 0; ++dcx) {
        int cx = x + dcx;
        if (cx < 0) continue;                 // only x==0, dcx==-1
        int bX = cx >> 3, lx = cx & 7;
#pragma unroll
        for (int dcy = -1; dcy <= 1; ++dcy) {
            int cy = ny + dcy;
            if ((unsigned)cy >= 128u) continue;   // cy==-1 at Yb==0 (cy==127 valid/empty)
            int bY = cy >> 3, ly = cy & 7;
            int liBase = (lx << 6) | (ly << 3);
#pragma unroll
            for (int sp = 0; sp < 2; ++sp) {
                int bZ, l0, l1;
                if (sp == 0) {
                    bZ = bZ0; l0 = cz_lo & 7; l1 = (bZ0 == bZ1) ? (cz_hi & 7) : 7;
                } else {
                    if (bZ1 == bZ0) break;
                    bZ = bZ1; l0 = 0; l1 = cz_hi & 7;
                }
                const unsigned int* bs =
                    binstarts + (size_t)((bX << 8) | (bY << 4) | bZ) * SPB + liBase;
                unsigned int s0 = bs[l0], e0 = bs[l1 + 1];
                for (unsigned int k = s0; k < e0; ++k) {
                    float4 a = rec[2 * (size_t)k];
                    float4 b = rec[2 * (size_t)k + 1];
                    float fx = a.x - (float)cx;
                    float fy = a.y - (float)cy;
                    int cz = (int)a.z;
                    float fz = a.z - (float)cz;
                    float wx = (dcx == -1) ? fx : 1.0f - fx;   // folds per unrolled dcx
                    int dz = cz - nz;                          // -1, 0, or 1
                    float wz0 = (dz == -1) ? fz : ((dz == 0) ? 1.0f - fz : 0.0f);
                    float wz1 = (dz == 0) ? fz : ((dz == 1) ? 1.0f - fz : 0.0f);
                    float m = b.w;
                    if (dcy <= 0) {           // node v=0 active (weight: dcy==-1 ? fy : 1-fy)
                        float wy = (dcy == -1) ? fy : 1.0f - fy;
                        float wm = wx * wy * m;
                        float w0 = wm * wz0, w1 = wm * wz1;
                        acc[0][0].x += w0; acc[0][0].y += w0 * b.x;
                        acc[0][0].z += w0 * b.y; acc[0][0].w += w0 * b.z;
                        acc[0][1].x += w1; acc[0][1].y += w1 * b.x;
                        acc[0][1].z += w1 * b.y; acc[0][1].w += w1 * b.z;
                    }
                    if (dcy >= 0) {           // node v=1 active (weight: dcy==0 ? fy : 1-fy)
                        float wy = (dcy == 0) ? fy : 1.0f - fy;
                        float wm = wx * wy * m;
                        float w0 = wm * wz0, w1 = wm * wz1;
                        acc[1][0].x += w0; acc[1][0].y += w0 * b.x;
                        acc[1][0].z += w0 * b.y; acc[1][0].w += w0 * b.z;
                        acc[1][1].x += w1; acc[1][1].y += w1 * b.x;
                        acc[1][1].z += w1 * b.y; acc[1][1].w += w1 * b.z;
                    }
                }
            }
        }
    }

#pragma unroll
    for (int v = 0; v < 2; ++v)
#pragma unroll
        for (int w = 0; w < 2; ++w) {
            float4 gacc = acc[v][w];
            float inv = 1.0f / fmaxf(gacc.x, EPS);
            int node = (((x << 7) | (ny + v)) << 7) | (nz + w);
            grid[node] = make_float4(gacc.y * inv, gacc.z * inv, gacc.w * inv, 0.0f);
        }
}

// ---------------- G2P: one workgroup per bin (contiguous sorted points) ----------------
__global__ __launch_bounds__(256) void g2p_kernelC(const float4* __restrict__ rec,
                                                   const unsigned int* __restrict__ binstarts,
                                                   const float4* __restrict__ grid,
                                                   float* __restrict__ out) {
    int bin = blockIdx.x;
    unsigned int bb = binstarts[(size_t)bin * SPB];
    unsigned int cnt = binstarts[(size_t)bin * SPB + 512] - bb;
    for (unsigned int k = threadIdx.x; k < cnt; k += 256) {
        float4 a = rec[(size_t)(bb + k) * 2];
        int bx = (int)a.x, by = (int)a.y, bz = (int)a.z;
        float fx = a.x - (float)bx, fy = a.y - (float)by, fz = a.z - (float)bz;
        float wx[2] = {1.0f - fx, fx};
        float wy[2] = {1.0f - fy, fy};
        float wz[2] = {1.0f - fz, fz};
        float ox = 0.f, oy = 0.f, oz = 0.f;
#pragma unroll
        for (int i = 0; i < 2; ++i) {
#pragma unroll
            for (int j = 0; j < 2; ++j) {
#pragma unroll
                for (int l = 0; l < 2; ++l) {
                    int node = (((((bx + i) & GMASK) << 7) | ((by + j) & GMASK)) << 7) | ((bz + l) & GMASK);
                    float w = wx[i] * wy[j] * wz[l];
                    float4 gv = grid[node];
                    ox += w * gv.x;
                    oy += w * gv.y;
                    oz += w * gv.z;
                }
            }
        }
        unsigned int oi = __float_as_uint(a.w);
        out[3 * (size_t)oi + 0] = ox;
        out[3 * (size_t)oi + 1] = oy;
        out[3 * (size_t)oi + 2] = oz;
    }
}

// ---------------- fallback (atomic path, needs only 32 MiB) ----------------
__global__ __launch_bounds__(256) void p2g_atomic_kernel(const float* __restrict__ pos,
                                                         const float* __restrict__ vel,
                                                         const float* __restrict__ mass,
                                                         float4* __restrict__ grid, int n) {
    int i = blockIdx.x * blockDim.x + threadIdx.x;
    if (i >= n) return;
    float rx = pos[3 * i] * INV_CELL, ry = pos[3 * i + 1] * INV_CELL, rz = pos[3 * i + 2] * INV_CELL;
    int bx = (int)floorf(rx), by = (int)floorf(ry), bz = (int)floorf(rz);
    float wx[2] = {1.0f - (rx - bx), rx - bx}, wy[2] = {1.0f - (ry - by), ry - by}, wz[2] = {1.0f - (rz - bz), rz - bz};
    float m = mass[i], vx = vel[3 * i], vy = vel[3 * i + 1], vz = vel[3 * i + 2];
#pragma unroll
    for (int a = 0; a < 2; ++a)
#pragma unroll
        for (int b = 0; b < 2; ++b)
#pragma unroll
            for (int c = 0; c < 2; ++c) {
                float w = wx[a] * wy[b] * wz[c] * m;
                int idx = (((((bx + a) & GMASK) << 7) | ((by + b) & GMASK)) << 7) | ((bz + c) & GMASK);
                float* cell = (float*)(grid + idx);
                atomicAdd(cell + 0, w);
                atomicAdd(cell + 1, w * vx);
                atomicAdd(cell + 2, w * vy);
                atomicAdd(cell + 3, w * vz);
            }
}

__global__ __launch_bounds__(256) void gridvel_kernel(float4* __restrict__ grid) {
    int i = blockIdx.x * blockDim.x + threadIdx.x;
    if (i >= NCELLS) return;
    float4 g = grid[i];
    float inv = 1.0f / fmaxf(g.x, EPS);
    grid[i] = make_float4(g.y * inv, g.z * inv, g.w * inv, 0.0f);
}

__global__ __launch_bounds__(256) void g2p_plain_kernel(const float* __restrict__ pos,
                                                        const float4* __restrict__ grid,
                                                        float* __restrict__ out, int n) {
    int i = blockIdx.x * blockDim.x + threadIdx.x;
    if (i >= n) return;
    float rx = pos[3 * i] * INV_CELL, ry = pos[3 * i + 1] * INV_CELL, rz = pos[3 * i + 2] * INV_CELL;
    int bx = (int)floorf(rx), by = (int)floorf(ry), bz = (int)floorf(rz);
    float wx[2] = {1.0f - (rx - bx), rx - bx}, wy[2] = {1.0f - (ry - by), ry - by}, wz[2] = {1.0f - (rz - bz), rz - bz};
    float ox = 0, oy = 0, oz = 0;
#pragma unroll
    for (int a = 0; a < 2; ++a)
#pragma unroll
        for (int b = 0; b < 2; ++b)
#pragma unroll
            for (int c = 0; c < 2; ++c) {
                float w = wx[a] * wy[b] * wz[c];
                int idx = (((((bx + a) & GMASK) << 7) | ((by + b) & GMASK)) << 7) | ((bz + c) & GMASK);
                float4 g = grid[idx];
                ox += w * g.x; oy += w * g.y; oz += w * g.z;
            }
    out[3 * i] = ox; out[3 * i + 1] = oy; out[3 * i + 2] = oz;
}

extern "C" void kernel_launch(void* const* d_in, const int* in_sizes, int n_in,
                              void* d_out, int out_size, void* d_ws, size_t ws_size,
                              hipStream_t stream) {
    const float* pos  = (const float*)d_in[0];
    const float* vel  = (const float*)d_in[1];
    const float* mass = (const float*)d_in[2];
    float* out = (float*)d_out;
    int n = in_sizes[2];

    char* ws = (char*)d_ws;
    size_t off = 0;
    float4* grid = (float4*)(ws + off);                  off += (size_t)NCELLS * 16;          // 32 MiB
    float4* rec  = (float4*)(ws + off);                  off += (size_t)n * 32;               // 30.5 MiB
    unsigned int* binstarts = (unsigned int*)(ws + off); off += (size_t)NBINS * SPB * 4;      // 8.4 MiB
    unsigned int* cnt       = (unsigned int*)(ws + off); off += (size_t)NCHUNK * NBINS * 4;   // 8 MiB
    unsigned int* offs      = (unsigned int*)(ws + off); off += (size_t)NCHUNK * NBINS * 4;   // 8 MiB
    unsigned int* binTotal  = (unsigned int*)(ws + off); off += (size_t)NBINS * 4;
    unsigned int* binPrefix = (unsigned int*)(ws + off); off += (size_t)(NBINS + 8) * 4;
    size_t need = off;

    int pblocks = (n + 255) / 256;
    int chunk = (n + NCHUNK - 1) / NCHUNK;

    if (ws_size < need) {
        float4* g0 = (float4*)d_ws;
        hipMemsetAsync(d_ws, 0, (size_t)NCELLS * 16, stream);
        p2g_atomic_kernel<<<pblocks, 256, 0, stream>>>(pos, vel, mass, g0, n);
        gridvel_kernel<<<NCELLS / 256, 256, 0, stream>>>(g0);
        g2p_plain_kernel<<<pblocks, 256, 0, stream>>>(pos, g0, out, n);
        return;
    }

    hist_kernel<<<NCHUNK, 256, 0, stream>>>(pos, cnt, n, chunk);
    scan_cols_kernel<<<NBINS / 256, 256, 0, stream>>>(cnt, offs, binTotal);
    scan_bins_kernel<<<1, 256, 0, stream>>>(binTotal, binPrefix, n);
    scatter_dense_kernel<<<NCHUNK, 256, 0, stream>>>(pos, vel, mass, offs, binPrefix, rec, n, chunk);
    binsort_kernel<<<NBINS, 256, 0, stream>>>(binPrefix, rec, binstarts);
    p2g_block_kernel<<<(128 * 64 * 64) / 256, 256, 0, stream>>>(rec, binstarts, grid);
    g2p_kernelC<<<NBINS, 256, 0, stream>>>(rec, binstarts, grid, out);
}

// Round 9
// 159.219 us; speedup vs baseline: 2.0835x; 1.0673x over previous
//
#include <hip/hip_runtime.h>

#define GDIM 128
#define GMASK 127
#define NCELLS (GDIM * GDIM * GDIM)
#define INV_CELL 120.0f
#define EPS 1e-9f

#define BDIM 16                    // 8^3-cell blocks per axis
#define NBINS (BDIM * BDIM * BDIM) // 4096
#define SPB 513                    // starts entries per bin (512 cells + end)
#define STCAP 448                  // binsort LDS stage capacity (bin ~Binom mean 296, sd 17)
#define NCHUNK 512                 // point chunks (one block each in hist/scatter)
#define FCAP 736                   // fused-stage capacity (10^3-cell region: mean 579, sd 24)

// Dense record (32 B, interleaved):
//   rec[2s]   = {rx, ry, rz, bitcast(orig_idx)}   (r = pos * INV_CELL)
//   rec[2s+1] = {vx, vy, vz, mass}
// Bin b owns slots [binPrefix[b], binPrefix[b+1]); after binsort, records in a
// bin are sorted by (local cell, orig_idx) — a CANONICAL order, so the whole
// pipeline is bitwise deterministic regardless of atomic arrival order.

// ---------------- pass 1: per-chunk LDS histogram (no global atomics) ----------------
__global__ __launch_bounds__(256) void hist_kernel(const float* __restrict__ pos,
                                                   unsigned int* __restrict__ cnt,
                                                   int n, int chunk) {
    __shared__ unsigned int lh[NBINS];   // 16 KB
    int c = blockIdx.x, t = threadIdx.x;
    for (int j = t; j < NBINS; j += 256) lh[j] = 0;
    __syncthreads();
    int s = c * chunk, e = min(n, s + chunk);
    for (int i = s + t; i < e; i += 256) {
        int bx = (int)(pos[3 * i + 0] * INV_CELL);   // pos >= 0: trunc == floor
        int by = (int)(pos[3 * i + 1] * INV_CELL);
        int bz = (int)(pos[3 * i + 2] * INV_CELL);
        int bin = ((bx >> 3) << 8) | ((by >> 3) << 4) | (bz >> 3);
        atomicAdd(&lh[bin], 1u);
    }
    __syncthreads();
    unsigned int* row = cnt + (size_t)c * NBINS;
    for (int j = t; j < NBINS; j += 256) row[j] = lh[j];
}

// ---------------- pass 2a: column scan over [NCHUNK][NBINS] ----------------
__global__ __launch_bounds__(256) void scan_cols_kernel(const unsigned int* __restrict__ cnt,
                                                        unsigned int* __restrict__ offs,
                                                        unsigned int* __restrict__ binTotal) {
    int col = blockIdx.x * 256 + threadIdx.x;   // 4096 threads, one column each
    unsigned int acc = 0;
#pragma unroll 8
    for (int r = 0; r < NCHUNK; ++r) {
        unsigned int v = cnt[(size_t)r * NBINS + col];
        offs[(size_t)r * NBINS + col] = acc;
        acc += v;
    }
    binTotal[col] = acc;
}

// ---------------- pass 2b: exclusive scan over 4096 bin totals ----------------
__global__ __launch_bounds__(256) void scan_bins_kernel(const unsigned int* __restrict__ binTotal,
                                                        unsigned int* __restrict__ binPrefix,
                                                        int n) {
    __shared__ unsigned int sh[256];
    int t = threadIdx.x;
    unsigned int e[16], s = 0;
#pragma unroll
    for (int j = 0; j < 16; ++j) { e[j] = binTotal[t * 16 + j]; s += e[j]; }
    sh[t] = s;
    __syncthreads();
#pragma unroll
    for (int off = 1; off < 256; off <<= 1) {
        unsigned int add = (t >= off) ? sh[t - off] : 0u;
        __syncthreads();
        sh[t] += add;
        __syncthreads();
    }
    unsigned int run = sh[t] - s;
#pragma unroll
    for (int j = 0; j < 16; ++j) { binPrefix[t * 16 + j] = run; run += e[j]; }
    if (t == 255) binPrefix[NBINS] = (unsigned int)n;
}

// ---------------- pass 3: dense scatter (LDS offsets; slot order canonicalized later) ----------------
__global__ __launch_bounds__(256) void scatter_dense_kernel(const float* __restrict__ pos,
                                                            const float* __restrict__ vel,
                                                            const float* __restrict__ mass,
                                                            const unsigned int* __restrict__ offs,
                                                            const unsigned int* __restrict__ binPrefix,
                                                            float4* __restrict__ rec,
                                                            int n, int chunk) {
    __shared__ unsigned int lof[NBINS];   // 16 KB
    int c = blockIdx.x, t = threadIdx.x;
    const unsigned int* row = offs + (size_t)c * NBINS;
    for (int j = t; j < NBINS; j += 256) lof[j] = row[j] + binPrefix[j];
    __syncthreads();
    int s = c * chunk, e = min(n, s + chunk);
    for (int i = s + t; i < e; i += 256) {
        float rx = pos[3 * i + 0] * INV_CELL;
        float ry = pos[3 * i + 1] * INV_CELL;
        float rz = pos[3 * i + 2] * INV_CELL;
        int bin = ((((int)rx) >> 3) << 8) | ((((int)ry) >> 3) << 4) | (((int)rz) >> 3);
        unsigned int slot = atomicAdd(&lof[bin], 1u);
        size_t b2 = (size_t)slot * 2;
        rec[b2]     = make_float4(rx, ry, rz, __uint_as_float((unsigned int)i));
        rec[b2 + 1] = make_float4(vel[3 * i + 0], vel[3 * i + 1], vel[3 * i + 2], mass[i]);
    }
}

// ---------------- per-bin in-LDS counting sort by (cell, orig_idx) — DETERMINISTIC ----------------
__global__ __launch_bounds__(256) void binsort_kernel(const unsigned int* __restrict__ binPrefix,
                                                      float4* __restrict__ rec,
                                                      unsigned int* __restrict__ binstarts) {
    __shared__ float4 stage[STCAP * 2];      // 14.3 KB
    __shared__ unsigned int codeLi[STCAP];   // cell of staged point k
    __shared__ unsigned int dstA[STCAP];     // provisional slot, then final dst
    __shared__ unsigned int perm[STCAP];     // provisional dst -> k
    __shared__ unsigned int ccount[512];
    __shared__ unsigned int cstart[513];
    __shared__ unsigned int sh[256];

    int bin = blockIdx.x;
    int t = threadIdx.x;
    unsigned int base = binPrefix[bin];
    unsigned int cnt = binPrefix[bin + 1] - base;
    if (cnt > STCAP) cnt = STCAP;            // statistically never (8.8 sigma)
    ccount[t] = 0;
    ccount[t + 256] = 0;
    __syncthreads();

    size_t b2 = (size_t)base * 2;
    // A: stage + provisional per-cell slot (arrival order — canonicalized below)
    for (unsigned int k = t; k < cnt; k += 256) {
        float4 a = rec[b2 + 2 * k];
        float4 b = rec[b2 + 2 * k + 1];
        stage[2 * k] = a;
        stage[2 * k + 1] = b;
        int li = ((((int)a.x) & 7) << 6) | ((((int)a.y) & 7) << 3) | (((int)a.z) & 7);
        codeLi[k] = (unsigned)li;
        dstA[k] = atomicAdd(&ccount[li], 1u);   // provisional slot within cell
    }
    __syncthreads();

    // exclusive scan of ccount[512] -> cstart (deterministic: counts only)
    unsigned int c0 = ccount[2 * t], c1 = ccount[2 * t + 1], s = c0 + c1;
    sh[t] = s;
    __syncthreads();
#pragma unroll
    for (int off = 1; off < 256; off <<= 1) {
        unsigned int add = (t >= off) ? sh[t - off] : 0u;
        __syncthreads();
        sh[t] += add;
        __syncthreads();
    }
    unsigned int pre = sh[t] - s;
    cstart[2 * t] = pre;
    cstart[2 * t + 1] = pre + c0;
    if (t == 255) cstart[512] = cnt;
    __syncthreads();

    // build provisional inverse map perm[cstart[li] + slot] = k
    for (unsigned int k = t; k < cnt; k += 256)
        perm[cstart[codeLi[k]] + dstA[k]] = k;
    __syncthreads();

    // B: canonical rank within each cell by orig_idx (O(c^2), c ~ Poisson(0.58))
    for (int cell = t; cell < 512; cell += 256) {
        unsigned int c = ccount[cell];
        if (c == 0) continue;
        unsigned int s0 = cstart[cell];
        for (unsigned int a = 0; a < c; ++a) {
            unsigned int ka = perm[s0 + a];
            unsigned int oia = __float_as_uint(stage[2 * ka].w);
            unsigned int r = 0;
            for (unsigned int b = 0; b < c; ++b) {
                unsigned int kb = perm[s0 + b];
                unsigned int oib = __float_as_uint(stage[2 * kb].w);
                r += (oib < oia) ? 1u : 0u;
            }
            dstA[ka] = s0 + r;   // final dst: unique (oi distinct)
        }
    }
    __syncthreads();

    // C: write back in canonical order + binstarts
    for (unsigned int k = t; k < cnt; k += 256) {
        unsigned int dst = dstA[k];
        rec[b2 + 2 * dst]     = stage[2 * k];
        rec[b2 + 2 * dst + 1] = stage[2 * k + 1];
    }
    for (int i = t; i < SPB; i += 256)
        binstarts[(size_t)bin * SPB + i] = base + cstart[i];
}

// ---------------- FUSED P2G + grid-vel + G2P: one wg per 8^3 block, no global grid ----------------
// Stage the 10^3-cell record region (own + 1-cell halo) in LDS via contiguous
// spans, compute 9^3 node sums from LDS (fixed scan order => deterministic),
// divide, then G2P own points from LDS nodes. Columns: (dxi,dyi) in 10x10,
// cells d=-1..8 along z staged contiguously per column.
__global__ __launch_bounds__(256) void fused_pg_kernel(const float4* __restrict__ rec,
                                                       const unsigned int* __restrict__ binstarts,
                                                       float* __restrict__ out) {
    __shared__ float4 lrec[2 * FCAP];          // 23552 B
    __shared__ float4 nodes[729];              // 11664 B
    __shared__ unsigned short cst[100 * 11];   // 2200 B: start of cell d=k-1 per column (+end)
    __shared__ unsigned int   rSrc[300];       // 1200 B: global rec idx of each span
    __shared__ unsigned short rDst[301];       // 602 B: staged dst start (monotone)
    __shared__ unsigned short ownCum[65];      // 130 B
    __shared__ unsigned int   sh[128];         // 512 B scan temp

    int wg = blockIdx.x;
    int Z = wg & 15, Y = (wg >> 4) & 15, X = wg >> 8;
    int t = threadIdx.x;

    // ---- phase 1a: per-column span discovery (threads 0..99) ----
    unsigned int cnt_[10];
    unsigned int srcA = 0, srcB = 0, srcC = 0, colTotal = 0;
    if (t < 100) {
        int dxi = t / 10, dyi = t % 10;
        int cgx = 8 * X - 1 + dxi, cgy = 8 * Y - 1 + dyi;
#pragma unroll
        for (int k = 0; k < 10; ++k) cnt_[k] = 0;
        if ((unsigned)cgx < 128u && (unsigned)cgy < 128u) {
            int bX = cgx >> 3, bY = cgy >> 3;
            int li0 = ((cgx & 7) << 6) | ((cgy & 7) << 3);
            if (Z > 0) {   // cell d=-1 lives in bin Z-1 at lz=7
                const unsigned int* p = binstarts + (size_t)((bX << 8) | (bY << 4) | (Z - 1)) * SPB + li0 + 7;
                srcA = p[0];
                cnt_[0] = p[1] - p[0];
            }
            {              // cells d=0..7 in bin Z, lz=0..7 contiguous
                const unsigned int* p = binstarts + (size_t)((bX << 8) | (bY << 4) | Z) * SPB + li0;
                unsigned int prev = p[0];
                srcB = prev;
#pragma unroll
                for (int k = 1; k <= 8; ++k) {
                    unsigned int cur = p[k];
                    cnt_[k] = cur - prev;
                    prev = cur;
                }
            }
            if (Z < 15) {  // cell d=8 in bin Z+1 at lz=0
                const unsigned int* p = binstarts + (size_t)((bX << 8) | (bY << 4) | (Z + 1)) * SPB + li0;
                srcC = p[0];
                cnt_[9] = p[1] - p[0];
            }
        }
#pragma unroll
        for (int k = 0; k < 10; ++k) colTotal += cnt_[k];
        sh[t] = colTotal;
    } else if (t < 128) {
        sh[t] = 0;
    }
    __syncthreads();
    // inclusive scan over sh[0..127]
    for (int off = 1; off < 128; off <<= 1) {
        unsigned int add = 0;
        if (t < 128 && t >= off) add = sh[t - off];
        __syncthreads();
        if (t < 128) sh[t] += add;
        __syncthreads();
    }
    if (t < 100) {
        unsigned int run = sh[t] - colTotal;   // exclusive start of this column
        unsigned short c11[11];
#pragma unroll
        for (int k = 0; k < 10; ++k) {
            c11[k] = (unsigned short)min(run, (unsigned)FCAP);
            run += cnt_[k];
        }
        c11[10] = (unsigned short)min(run, (unsigned)FCAP);
#pragma unroll
        for (int k = 0; k < 11; ++k) cst[t * 11 + k] = c11[k];
        int r = t * 3;
        rSrc[r]     = srcA;  rDst[r]     = c11[0];
        rSrc[r + 1] = srcB;  rDst[r + 1] = c11[1];
        rSrc[r + 2] = srcC;  rDst[r + 2] = c11[9];
        if (t == 99) rDst[300] = c11[10];
    }
    __syncthreads();

    // ---- phase 1b: record-parallel staged copy ----
    unsigned int total = rDst[300];
    for (unsigned int q = t; q < total; q += 256) {
        int lo = 0, hi = 300;                 // largest r with rDst[r] <= q
        while (hi - lo > 1) {
            int mid = (lo + hi) >> 1;
            if ((unsigned int)rDst[mid] <= q) lo = mid; else hi = mid;
        }
        size_t src = (size_t)(rSrc[lo] + (q - rDst[lo])) * 2;
        lrec[2 * q]     = rec[src];
        lrec[2 * q + 1] = rec[src + 1];
    }

    // ---- phase 1c: own-column cumulative (cells d=0..7, cols dxi,dyi in 1..8) ----
    if (t < 64) {
        int col = ((t >> 3) + 1) * 10 + ((t & 7) + 1);
        sh[t] = (unsigned int)cst[col * 11 + 9] - (unsigned int)cst[col * 11 + 1];
    } else if (t < 128) {
        sh[t] = 0;
    }
    __syncthreads();
    for (int off = 1; off < 64; off <<= 1) {
        unsigned int add = 0;
        if (t < 64 && t >= off) add = sh[t - off];
        __syncthreads();
        if (t < 64) sh[t] += add;
        __syncthreads();
    }
    if (t < 64) ownCum[t + 1] = (unsigned short)sh[t];
    if (t == 0) ownCum[0] = 0;
    __syncthreads();   // lrec, cst, ownCum ready

    // ---- phase 2: 9^3 node sums from LDS, fixed order, no atomics ----
    for (int n = t; n < 729; n += 256) {
        int nx = n / 81, ny = (n / 9) % 9, nz = n % 9;
        int gnz = 8 * Z + nz;
        float macc = 0.f, mx = 0.f, my = 0.f, mz = 0.f;
#pragma unroll
        for (int i = 0; i < 2; ++i) {
            int cgx = 8 * X - 1 + nx + i;
#pragma unroll
            for (int j = 0; j < 2; ++j) {
                int cgy = 8 * Y - 1 + ny + j;
                int col = (nx + i) * 10 + (ny + j);
                unsigned int s0 = cst[col * 11 + nz];
                unsigned int e0 = cst[col * 11 + nz + 2];
                for (unsigned int k = s0; k < e0; ++k) {
                    float4 a = lrec[2 * k];
                    float4 b = lrec[2 * k + 1];
                    float fx = a.x - (float)cgx;
                    float fy = a.y - (float)cgy;
                    int cz = (int)a.z;
                    float fz = a.z - (float)cz;
                    float wx = i ? (1.0f - fx) : fx;
                    float wy = j ? (1.0f - fy) : fy;
                    float wz = (cz == gnz) ? (1.0f - fz) : fz;
                    float w = wx * wy * wz * b.w;
                    macc += w;
                    mx += w * b.x;
                    my += w * b.y;
                    mz += w * b.z;
                }
            }
        }
        float inv = 1.0f / fmaxf(macc, EPS);
        nodes[n] = make_float4(mx * inv, my * inv, mz * inv, 0.0f);
    }
    __syncthreads();

    // ---- phase 3: G2P for own points from LDS nodes ----
    unsigned int ownTotal = ownCum[64];
    for (unsigned int q = t; q < ownTotal; q += 256) {
        int lo = 0, hi = 64;                  // largest oc with ownCum[oc] <= q
        while (hi - lo > 1) {
            int mid = (lo + hi) >> 1;
            if ((unsigned int)ownCum[mid] <= q) lo = mid; else hi = mid;
        }
        int col = ((lo >> 3) + 1) * 10 + ((lo & 7) + 1);
        unsigned int kk = (unsigned int)cst[col * 11 + 1] + (q - (unsigned int)ownCum[lo]);
        float4 a = lrec[2 * kk];
        int gx = (int)a.x, gy = (int)a.y, gz = (int)a.z;
        float fx = a.x - (float)gx, fy = a.y - (float)gy, fz = a.z - (float)gz;
        int lx = gx - 8 * X, ly = gy - 8 * Y, lz = gz - 8 * Z;   // 0..7
        float wxa[2] = {1.0f - fx, fx};
        float wya[2] = {1.0f - fy, fy};
        float wza[2] = {1.0f - fz, fz};
        float ox = 0.f, oy = 0.f, oz = 0.f;
#pragma unroll
        for (int i = 0; i < 2; ++i) {
#pragma unroll
            for (int j = 0; j < 2; ++j) {
#pragma unroll
                for (int l = 0; l < 2; ++l) {
                    float4 nv = nodes[(lx + i) * 81 + (ly + j) * 9 + (lz + l)];
                    float w = wxa[i] * wya[j] * wza[l];
                    ox += w * nv.x;
                    oy += w * nv.y;
                    oz += w * nv.z;
                }
            }
        }
        unsigned int oi = __float_as_uint(a.w);
        out[3 * (size_t)oi + 0] = ox;
        out[3 * (size_t)oi + 1] = oy;
        out[3 * (size_t)oi + 2] = oz;
    }
}

// ---------------- fallback (atomic path, needs only 32 MiB) ----------------
__global__ __launch_bounds__(256) void p2g_atomic_kernel(const float* __restrict__ pos,
                                                         const float* __restrict__ vel,
                                                         const float* __restrict__ mass,
                                                         float4* __restrict__ grid, int n) {
    int i = blockIdx.x * blockDim.x + threadIdx.x;
    if (i >= n) return;
    float rx = pos[3 * i] * INV_CELL, ry = pos[3 * i + 1] * INV_CELL, rz = pos[3 * i + 2] * INV_CELL;
    int bx = (int)floorf(rx), by = (int)floorf(ry), bz = (int)floorf(rz);
    float wx[2] = {1.0f - (rx - bx), rx - bx}, wy[2] = {1.0f - (ry - by), ry - by}, wz[2] = {1.0f - (rz - bz), rz - bz};
    float m = mass[i], vx = vel[3 * i], vy = vel[3 * i + 1], vz = vel[3 * i + 2];
#pragma unroll
    for (int a = 0; a < 2; ++a)
#pragma unroll
        for (int b = 0; b < 2; ++b)
#pragma unroll
            for (int c = 0; c < 2; ++c) {
                float w = wx[a] * wy[b] * wz[c] * m;
                int idx = (((((bx + a) & GMASK) << 7) | ((by + b) & GMASK)) << 7) | ((bz + c) & GMASK);
                float* cell = (float*)(grid + idx);
                atomicAdd(cell + 0, w);
                atomicAdd(cell + 1, w * vx);
                atomicAdd(cell + 2, w * vy);
                atomicAdd(cell + 3, w * vz);
            }
}

__global__ __launch_bounds__(256) void gridvel_kernel(float4* __restrict__ grid) {
    int i = blockIdx.x * blockDim.x + threadIdx.x;
    if (i >= NCELLS) return;
    float4 g = grid[i];
    float inv = 1.0f / fmaxf(g.x, EPS);
    grid[i] = make_float4(g.y * inv, g.z * inv, g.w * inv, 0.0f);
}

__global__ __launch_bounds__(256) void g2p_plain_kernel(const float* __restrict__ pos,
                                                        const float4* __restrict__ grid,
                                                        float* __restrict__ out, int n) {
    int i = blockIdx.x * blockDim.x + threadIdx.x;
    if (i >= n) return;
    float rx = pos[3 * i] * INV_CELL, ry = pos[3 * i + 1] * INV_CELL, rz = pos[3 * i + 2] * INV_CELL;
    int bx = (int)floorf(rx), by = (int)floorf(ry), bz = (int)floorf(rz);
    float wx[2] = {1.0f - (rx - bx), rx - bx}, wy[2] = {1.0f - (ry - by), ry - by}, wz[2] = {1.0f - (rz - bz), rz - bz};
    float ox = 0, oy = 0, oz = 0;
#pragma unroll
    for (int a = 0; a < 2; ++a)
#pragma unroll
        for (int b = 0; b < 2; ++b)
#pragma unroll
            for (int c = 0; c < 2; ++c) {
                float w = wx[a] * wy[b] * wz[c];
                int idx = (((((bx + a) & GMASK) << 7) | ((by + b) & GMASK)) << 7) | ((bz + c) & GMASK);
                float4 g = grid[idx];
                ox += w * g.x; oy += w * g.y; oz += w * g.z;
            }
    out[3 * i] = ox; out[3 * i + 1] = oy; out[3 * i + 2] = oz;
}

extern "C" void kernel_launch(void* const* d_in, const int* in_sizes, int n_in,
                              void* d_out, int out_size, void* d_ws, size_t ws_size,
                              hipStream_t stream) {
    const float* pos  = (const float*)d_in[0];
    const float* vel  = (const float*)d_in[1];
    const float* mass = (const float*)d_in[2];
    float* out = (float*)d_out;
    int n = in_sizes[2];

    char* ws = (char*)d_ws;
    size_t off = 0;
    float4* rec  = (float4*)(ws + off);                  off += (size_t)n * 32;               // 30.5 MiB
    unsigned int* binstarts = (unsigned int*)(ws + off); off += (size_t)NBINS * SPB * 4;      // 8.4 MiB
    unsigned int* cnt       = (unsigned int*)(ws + off); off += (size_t)NCHUNK * NBINS * 4;   // 8 MiB
    unsigned int* offs      = (unsigned int*)(ws + off); off += (size_t)NCHUNK * NBINS * 4;   // 8 MiB
    unsigned int* binTotal  = (unsigned int*)(ws + off); off += (size_t)NBINS * 4;
    unsigned int* binPrefix = (unsigned int*)(ws + off); off += (size_t)(NBINS + 8) * 4;
    size_t need = off;

    int pblocks = (n + 255) / 256;
    int chunk = (n + NCHUNK - 1) / NCHUNK;

    if (ws_size < need) {
        float4* g0 = (float4*)d_ws;   // fallback path owns the whole workspace
        hipMemsetAsync(d_ws, 0, (size_t)NCELLS * 16, stream);
        p2g_atomic_kernel<<<pblocks, 256, 0, stream>>>(pos, vel, mass, g0, n);
        gridvel_kernel<<<NCELLS / 256, 256, 0, stream>>>(g0);
        g2p_plain_kernel<<<pblocks, 256, 0, stream>>>(pos, g0, out, n);
        return;
    }

    hist_kernel<<<NCHUNK, 256, 0, stream>>>(pos, cnt, n, chunk);
    scan_cols_kernel<<<NBINS / 256, 256, 0, stream>>>(cnt, offs, binTotal);
    scan_bins_kernel<<<1, 256, 0, stream>>>(binTotal, binPrefix, n);
    scatter_dense_kernel<<<NCHUNK, 256, 0, stream>>>(pos, vel, mass, offs, binPrefix, rec, n, chunk);
    binsort_kernel<<<NBINS, 256, 0, stream>>>(binPrefix, rec, binstarts);
    fused_pg_kernel<<<NBINS, 256, 0, stream>>>(rec, binstarts, out);
}